// Round 1
// baseline (5653.104 us; speedup 1.0000x reference)
//
#include <hip/hip_runtime.h>
#include <cstdint>
#include <cstddef>

constexpr int DIMS = 128;

// ---------------- degree ----------------
__global__ void k_count(const int* __restrict__ dst, int* __restrict__ cnt, int E) {
    int e = blockIdx.x * blockDim.x + threadIdx.x;
    if (e < E) atomicAdd(&cnt[dst[e]], 1);
}

// in-place: reads int count, writes float rsqrt(deg) (deg = cnt + 1 self loop)
__global__ void k_dinv(void* __restrict__ p, int N) {
    int i = blockIdx.x * blockDim.x + threadIdx.x;
    if (i < N) {
        int c = ((const int*)p)[i];
        ((float*)p)[i] = rsqrtf((float)(c + 1));
    }
}

// ---------------- aggregation: agg = \hat{A} @ x ----------------
// self-loop term: agg[i] = dinv[i]^2 * x[i]
__global__ void k_agg_init(const float4* __restrict__ x4, const float* __restrict__ dinv,
                           float4* __restrict__ agg4, int N) {
    int idx = blockIdx.x * blockDim.x + threadIdx.x;  // over N*32 float4s
    if (idx >= N * 32) return;
    int i = idx >> 5;
    float w = dinv[i]; w *= w;
    float4 v = x4[idx];
    v.x *= w; v.y *= w; v.z *= w; v.w *= w;
    agg4[idx] = v;
}

// edge scatter: agg[dst] += dinv[src]*dinv[dst] * x[src]
__global__ void k_agg_edges(const int* __restrict__ src, const int* __restrict__ dst,
                            const float* __restrict__ dinv, const float* __restrict__ X,
                            float* __restrict__ agg, int E) {
    int t = blockIdx.x * blockDim.x + threadIdx.x;  // E*32 threads
    int e = t >> 5;
    if (e >= E) return;
    int q = t & 31;
    int s = src[e], d = dst[e];
    float w = dinv[s] * dinv[d];
    const float4 v = *(const float4*)&X[(size_t)s * DIMS + q * 4];
    float* p = &agg[(size_t)d * DIMS + q * 4];
    unsafeAtomicAdd(p + 0, v.x * w);
    unsafeAtomicAdd(p + 1, v.y * w);
    unsafeAtomicAdd(p + 2, v.z * w);
    unsafeAtomicAdd(p + 3, v.w * w);
}

// ---------------- fused dual-GEMM + coupling epilogue ----------------
// s = tanh(A@Ws + bs); t = A@Wt + bt; Out = Xo * exp(s) + t
// A may alias Out (row-block in-place safe: all A reads precede the final
// __syncthreads; stores follow it; blocks touch only their own rows).
__global__ __launch_bounds__(256) void k_gemm_couple(
    const float* A, const float* __restrict__ Ws, const float* __restrict__ bs,
    const float* __restrict__ Wt, const float* __restrict__ bt,
    const float* __restrict__ Xo, float* Out, int N)
{
    constexpr int TM = 64, TK = 16;
    __shared__ float As[TK][TM + 4];
    __shared__ float Ss[TK][DIMS];
    __shared__ float St[TK][DIMS];
    const int tid = threadIdx.x;
    const int ty = tid >> 4, tx = tid & 15;
    const int r0 = ty * 4, c0 = tx * 8;
    const int block_row = blockIdx.x * TM;

    float acc_s[4][8], acc_t[4][8];
#pragma unroll
    for (int r = 0; r < 4; ++r)
#pragma unroll
        for (int c = 0; c < 8; ++c) { acc_s[r][c] = 0.f; acc_t[r][c] = 0.f; }

    const int ar = tid >> 2;  // 0..63: row within tile for A staging
    const int aq = tid & 3;   // 0..3: float4 within TK
    int arow = block_row + ar;
    if (arow >= N) arow = N - 1;

    for (int k0 = 0; k0 < DIMS; k0 += TK) {
        __syncthreads();
        {
            float4 v = *(const float4*)&A[(size_t)arow * DIMS + k0 + aq * 4];
            As[aq * 4 + 0][ar] = v.x;
            As[aq * 4 + 1][ar] = v.y;
            As[aq * 4 + 2][ar] = v.z;
            As[aq * 4 + 3][ar] = v.w;
        }
#pragma unroll
        for (int i = 0; i < 2; ++i) {
            int idx = tid + i * 256;  // float4 index 0..511 within 16x128 strip
            int kk = idx >> 5;
            int j4 = idx & 31;
            *(float4*)&Ss[kk][j4 * 4] = *(const float4*)&Ws[(size_t)(k0 + kk) * DIMS + j4 * 4];
            *(float4*)&St[kk][j4 * 4] = *(const float4*)&Wt[(size_t)(k0 + kk) * DIMS + j4 * 4];
        }
        __syncthreads();
#pragma unroll
        for (int k = 0; k < TK; ++k) {
            float4 av = *(const float4*)&As[k][r0];
            float a[4] = {av.x, av.y, av.z, av.w};
            float ws8[8], wt8[8];
            *(float4*)&ws8[0] = *(const float4*)&Ss[k][c0];
            *(float4*)&ws8[4] = *(const float4*)&Ss[k][c0 + 4];
            *(float4*)&wt8[0] = *(const float4*)&St[k][c0];
            *(float4*)&wt8[4] = *(const float4*)&St[k][c0 + 4];
#pragma unroll
            for (int r = 0; r < 4; ++r)
#pragma unroll
                for (int c = 0; c < 8; ++c) {
                    acc_s[r][c] = fmaf(a[r], ws8[c], acc_s[r][c]);
                    acc_t[r][c] = fmaf(a[r], wt8[c], acc_t[r][c]);
                }
        }
    }

    float bsv[8], btv[8];
    *(float4*)&bsv[0] = *(const float4*)&bs[c0];
    *(float4*)&bsv[4] = *(const float4*)&bs[c0 + 4];
    *(float4*)&btv[0] = *(const float4*)&bt[c0];
    *(float4*)&btv[4] = *(const float4*)&bt[c0 + 4];
#pragma unroll
    for (int r = 0; r < 4; ++r) {
        int row = block_row + r0 + r;
        if (row < N) {
            float xo[8];
            *(float4*)&xo[0] = *(const float4*)&Xo[(size_t)row * DIMS + c0];
            *(float4*)&xo[4] = *(const float4*)&Xo[(size_t)row * DIMS + c0 + 4];
            float o[8];
#pragma unroll
            for (int c = 0; c < 8; ++c) {
                float s = tanhf(acc_s[r][c] + bsv[c]);
                float t = acc_t[r][c] + btv[c];
                o[c] = xo[c] * expf(s) + t;
            }
            *(float4*)&Out[(size_t)row * DIMS + c0] = *(const float4*)&o[0];
            *(float4*)&Out[(size_t)row * DIMS + c0 + 4] = *(const float4*)&o[4];
        }
    }
}

extern "C" void kernel_launch(void* const* d_in, const int* in_sizes, int n_in,
                              void* d_out, int out_size, void* d_ws, size_t ws_size,
                              hipStream_t stream) {
    const float* x_main  = (const float*)d_in[0];
    const float* x_guide = (const float*)d_in[1];
    const int*   ei      = (const int*)d_in[2];
    const float* Ws1 = (const float*)d_in[3];
    const float* bs1 = (const float*)d_in[4];
    const float* Wt1 = (const float*)d_in[5];
    const float* bt1 = (const float*)d_in[6];
    const float* Ws2 = (const float*)d_in[7];
    const float* bs2 = (const float*)d_in[8];
    const float* Wt2 = (const float*)d_in[9];
    const float* bt2 = (const float*)d_in[10];

    const int N = in_sizes[0] / DIMS;
    const int E = in_sizes[2] / 2;
    const int* src = ei;       // edge_index[0]
    const int* dst = ei + E;   // edge_index[1]

    float* out_main  = (float*)d_out;
    float* out_guide = out_main + (size_t)N * DIMS;
    float* agg  = out_guide;          // scratch aliasing the second output
    float* dinv = (float*)d_ws;       // N floats (int counts first, in place)

    // degree -> dinv
    hipMemsetAsync(d_ws, 0, (size_t)N * sizeof(int), stream);
    k_count<<<(E + 255) / 256, 256, 0, stream>>>(dst, (int*)d_ws, E);
    k_dinv<<<(N + 255) / 256, 256, 0, stream>>>(d_ws, N);

    const int agg_init_grid = (N * 32 + 255) / 256;
    const int agg_edge_grid = (E * 32 + 255) / 256;
    const int gemm_grid     = (N + 63) / 64;

    // ---- stage 1: agg1 = Â @ x_guide ; x_main* = x_main*exp(s1)+t1 ----
    k_agg_init<<<agg_init_grid, 256, 0, stream>>>((const float4*)x_guide, dinv, (float4*)agg, N);
    k_agg_edges<<<agg_edge_grid, 256, 0, stream>>>(src, dst, dinv, x_guide, agg, E);
    k_gemm_couple<<<gemm_grid, 256, 0, stream>>>(agg, Ws1, bs1, Wt1, bt1, x_main, out_main, N);

    // ---- stage 2: agg2 = Â @ x_main* ; x_guide* = x_guide*exp(s2)+t2 ----
    k_agg_init<<<agg_init_grid, 256, 0, stream>>>((const float4*)out_main, dinv, (float4*)agg, N);
    k_agg_edges<<<agg_edge_grid, 256, 0, stream>>>(src, dst, dinv, out_main, agg, E);
    k_gemm_couple<<<gemm_grid, 256, 0, stream>>>(agg, Ws2, bs2, Wt2, bt2, x_guide, out_guide, N);
}

// Round 2
// 607.638 us; speedup vs baseline: 9.3034x; 9.3034x over previous
//
#include <hip/hip_runtime.h>
#include <cstdint>
#include <cstddef>

constexpr int DIMS = 128;

// ---------------- degree ----------------
__global__ void k_count(const int* __restrict__ dst, int* __restrict__ cnt, int E) {
    int e = blockIdx.x * blockDim.x + threadIdx.x;
    if (e < E) atomicAdd(&cnt[dst[e]], 1);
}

// dinv[i] = rsqrt(cnt[i] + 1)   (keeps cnt intact)
__global__ void k_dinv2(const int* __restrict__ cnt, float* __restrict__ dinv, int N) {
    int i = blockIdx.x * blockDim.x + threadIdx.x;
    if (i < N) dinv[i] = rsqrtf((float)(cnt[i] + 1));
}

// row_ptr[i] = bump-allocated range of size cnt[i] (unordered CSR buckets).
// Wave-level exclusive scan + one atomic per wave.
__global__ void k_alloc(const int* __restrict__ cnt, int* __restrict__ row_ptr,
                        int* __restrict__ bump, int N) {
    int i = blockIdx.x * blockDim.x + threadIdx.x;
    int lane = threadIdx.x & 63;
    int v = (i < N) ? cnt[i] : 0;
    int x = v;
#pragma unroll
    for (int d = 1; d < 64; d <<= 1) {
        int y = __shfl_up(x, d);
        if (lane >= d) x += y;
    }
    int total = __shfl(x, 63);          // wave sum
    int base = 0;
    if (lane == 0) base = atomicAdd(bump, total);
    base = __shfl(base, 0);
    if (i < N) row_ptr[i] = base + x - v;   // exclusive prefix within wave
}

// bucket fill: col[pos]=src, wgt[pos]=dinv[src]*dinv[dst]
__global__ void k_fill(const int* __restrict__ src, const int* __restrict__ dst,
                       const int* __restrict__ row_ptr, int* __restrict__ cursor,
                       const float* __restrict__ dinv,
                       int* __restrict__ col, float* __restrict__ wgt, int E) {
    int e = blockIdx.x * blockDim.x + threadIdx.x;
    if (e >= E) return;
    int s = src[e], d = dst[e];
    int pos = row_ptr[d] + atomicAdd(&cursor[d], 1);
    col[pos] = s;
    wgt[pos] = dinv[s] * dinv[d];
}

// ---------------- deterministic gather: agg = \hat{A} @ x ----------------
// 32 lanes per node, float4 per lane (512B coalesced row reads).
__global__ __launch_bounds__(256) void k_gather(
    const float4* __restrict__ X4, const float* __restrict__ dinv,
    const int* __restrict__ row_ptr, const int* __restrict__ cnt,
    const int* __restrict__ col, const float* __restrict__ wgt,
    float4* __restrict__ agg4, int N)
{
    int t = blockIdx.x * blockDim.x + threadIdx.x;
    int node = t >> 5;
    if (node >= N) return;
    int lane = t & 31;

    float ds = dinv[node];
    float w0 = ds * ds;                       // self-loop weight
    float4 acc = X4[(size_t)node * 32 + lane];
    acc.x *= w0; acc.y *= w0; acc.z *= w0; acc.w *= w0;

    int beg = row_ptr[node];
    int m = cnt[node];
    int j = 0;
    for (; j + 1 < m; j += 2) {               // dual-stream for ILP
        int s0 = col[beg + j], s1 = col[beg + j + 1];
        float wa = wgt[beg + j], wb = wgt[beg + j + 1];
        float4 v0 = X4[(size_t)s0 * 32 + lane];
        float4 v1 = X4[(size_t)s1 * 32 + lane];
        acc.x = fmaf(wa, v0.x, acc.x); acc.y = fmaf(wa, v0.y, acc.y);
        acc.z = fmaf(wa, v0.z, acc.z); acc.w = fmaf(wa, v0.w, acc.w);
        acc.x = fmaf(wb, v1.x, acc.x); acc.y = fmaf(wb, v1.y, acc.y);
        acc.z = fmaf(wb, v1.z, acc.z); acc.w = fmaf(wb, v1.w, acc.w);
    }
    if (j < m) {
        int s0 = col[beg + j];
        float wa = wgt[beg + j];
        float4 v0 = X4[(size_t)s0 * 32 + lane];
        acc.x = fmaf(wa, v0.x, acc.x); acc.y = fmaf(wa, v0.y, acc.y);
        acc.z = fmaf(wa, v0.z, acc.z); acc.w = fmaf(wa, v0.w, acc.w);
    }
    agg4[(size_t)node * 32 + lane] = acc;
}

// ---------------- fallback (atomic scatter) kernels ----------------
__global__ void k_dinv_inplace(void* __restrict__ p, int N) {
    int i = blockIdx.x * blockDim.x + threadIdx.x;
    if (i < N) {
        int c = ((const int*)p)[i];
        ((float*)p)[i] = rsqrtf((float)(c + 1));
    }
}

__global__ void k_agg_init(const float4* __restrict__ x4, const float* __restrict__ dinv,
                           float4* __restrict__ agg4, int N) {
    int idx = blockIdx.x * blockDim.x + threadIdx.x;
    if (idx >= N * 32) return;
    int i = idx >> 5;
    float w = dinv[i]; w *= w;
    float4 v = x4[idx];
    v.x *= w; v.y *= w; v.z *= w; v.w *= w;
    agg4[idx] = v;
}

__global__ void k_agg_edges(const int* __restrict__ src, const int* __restrict__ dst,
                            const float* __restrict__ dinv, const float* __restrict__ X,
                            float* __restrict__ agg, int E) {
    int t = blockIdx.x * blockDim.x + threadIdx.x;
    int e = t >> 5;
    if (e >= E) return;
    int q = t & 31;
    int s = src[e], d = dst[e];
    float w = dinv[s] * dinv[d];
    const float4 v = *(const float4*)&X[(size_t)s * DIMS + q * 4];
    float* p = &agg[(size_t)d * DIMS + q * 4];
    unsafeAtomicAdd(p + 0, v.x * w);
    unsafeAtomicAdd(p + 1, v.y * w);
    unsafeAtomicAdd(p + 2, v.z * w);
    unsafeAtomicAdd(p + 3, v.w * w);
}

// ---------------- fused dual-GEMM + coupling epilogue ----------------
// s = tanh(A@Ws + bs); t = A@Wt + bt; Out = Xo * exp(s) + t
// A may alias Out (row-block in-place safe).
__global__ __launch_bounds__(256) void k_gemm_couple(
    const float* A, const float* __restrict__ Ws, const float* __restrict__ bs,
    const float* __restrict__ Wt, const float* __restrict__ bt,
    const float* __restrict__ Xo, float* Out, int N)
{
    constexpr int TM = 64, TK = 16;
    __shared__ float As[TK][TM + 4];
    __shared__ float Ss[TK][DIMS];
    __shared__ float St[TK][DIMS];
    const int tid = threadIdx.x;
    const int ty = tid >> 4, tx = tid & 15;
    const int r0 = ty * 4, c0 = tx * 8;
    const int block_row = blockIdx.x * TM;

    float acc_s[4][8], acc_t[4][8];
#pragma unroll
    for (int r = 0; r < 4; ++r)
#pragma unroll
        for (int c = 0; c < 8; ++c) { acc_s[r][c] = 0.f; acc_t[r][c] = 0.f; }

    const int ar = tid >> 2;
    const int aq = tid & 3;
    int arow = block_row + ar;
    if (arow >= N) arow = N - 1;

    for (int k0 = 0; k0 < DIMS; k0 += TK) {
        __syncthreads();
        {
            float4 v = *(const float4*)&A[(size_t)arow * DIMS + k0 + aq * 4];
            As[aq * 4 + 0][ar] = v.x;
            As[aq * 4 + 1][ar] = v.y;
            As[aq * 4 + 2][ar] = v.z;
            As[aq * 4 + 3][ar] = v.w;
        }
#pragma unroll
        for (int i = 0; i < 2; ++i) {
            int idx = tid + i * 256;
            int kk = idx >> 5;
            int j4 = idx & 31;
            *(float4*)&Ss[kk][j4 * 4] = *(const float4*)&Ws[(size_t)(k0 + kk) * DIMS + j4 * 4];
            *(float4*)&St[kk][j4 * 4] = *(const float4*)&Wt[(size_t)(k0 + kk) * DIMS + j4 * 4];
        }
        __syncthreads();
#pragma unroll
        for (int k = 0; k < TK; ++k) {
            float4 av = *(const float4*)&As[k][r0];
            float a[4] = {av.x, av.y, av.z, av.w};
            float ws8[8], wt8[8];
            *(float4*)&ws8[0] = *(const float4*)&Ss[k][c0];
            *(float4*)&ws8[4] = *(const float4*)&Ss[k][c0 + 4];
            *(float4*)&wt8[0] = *(const float4*)&St[k][c0];
            *(float4*)&wt8[4] = *(const float4*)&St[k][c0 + 4];
#pragma unroll
            for (int r = 0; r < 4; ++r)
#pragma unroll
                for (int c = 0; c < 8; ++c) {
                    acc_s[r][c] = fmaf(a[r], ws8[c], acc_s[r][c]);
                    acc_t[r][c] = fmaf(a[r], wt8[c], acc_t[r][c]);
                }
        }
    }

    float bsv[8], btv[8];
    *(float4*)&bsv[0] = *(const float4*)&bs[c0];
    *(float4*)&bsv[4] = *(const float4*)&bs[c0 + 4];
    *(float4*)&btv[0] = *(const float4*)&bt[c0];
    *(float4*)&btv[4] = *(const float4*)&bt[c0 + 4];
#pragma unroll
    for (int r = 0; r < 4; ++r) {
        int row = block_row + r0 + r;
        if (row < N) {
            float xo[8];
            *(float4*)&xo[0] = *(const float4*)&Xo[(size_t)row * DIMS + c0];
            *(float4*)&xo[4] = *(const float4*)&Xo[(size_t)row * DIMS + c0 + 4];
            float o[8];
#pragma unroll
            for (int c = 0; c < 8; ++c) {
                float s = tanhf(acc_s[r][c] + bsv[c]);
                float t = acc_t[r][c] + btv[c];
                o[c] = xo[c] * expf(s) + t;
            }
            *(float4*)&Out[(size_t)row * DIMS + c0] = *(const float4*)&o[0];
            *(float4*)&Out[(size_t)row * DIMS + c0 + 4] = *(const float4*)&o[4];
        }
    }
}

extern "C" void kernel_launch(void* const* d_in, const int* in_sizes, int n_in,
                              void* d_out, int out_size, void* d_ws, size_t ws_size,
                              hipStream_t stream) {
    const float* x_main  = (const float*)d_in[0];
    const float* x_guide = (const float*)d_in[1];
    const int*   ei      = (const int*)d_in[2];
    const float* Ws1 = (const float*)d_in[3];
    const float* bs1 = (const float*)d_in[4];
    const float* Wt1 = (const float*)d_in[5];
    const float* bt1 = (const float*)d_in[6];
    const float* Ws2 = (const float*)d_in[7];
    const float* bs2 = (const float*)d_in[8];
    const float* Wt2 = (const float*)d_in[9];
    const float* bt2 = (const float*)d_in[10];

    const int N = in_sizes[0] / DIMS;
    const int E = in_sizes[2] / 2;
    const int* src = ei;
    const int* dst = ei + E;

    float* out_main  = (float*)d_out;
    float* out_guide = out_main + (size_t)N * DIMS;
    float* agg = out_guide;   // scratch aliasing second output (written last)

    const int gemm_grid = (N + 63) / 64;
    const int gather_grid = (N * 32 + 255) / 256;

    // ws layout (CSR path)
    int*   cnt     = (int*)d_ws;            // N
    int*   row_ptr = cnt + N;               // N
    int*   cursor  = row_ptr + N;           // N
    int*   bump    = cursor + N;            // 16 (aligned pad)
    float* dinv    = (float*)(bump + 16);   // N
    int*   col     = (int*)(dinv + N);      // E
    float* wgt     = (float*)(col + E);     // E
    size_t needed  = (size_t)(4 * N + 16) * 4 + (size_t)E * 8;

    if (ws_size >= needed) {
        // ---- CSR build (once, reused by both stages) ----
        hipMemsetAsync(cnt, 0, (size_t)N * sizeof(int), stream);
        hipMemsetAsync(bump, 0, sizeof(int), stream);
        k_count<<<(E + 255) / 256, 256, 0, stream>>>(dst, cnt, E);
        k_dinv2<<<(N + 255) / 256, 256, 0, stream>>>(cnt, dinv, N);
        k_alloc<<<(N + 255) / 256, 256, 0, stream>>>(cnt, row_ptr, bump, N);
        hipMemsetAsync(cursor, 0, (size_t)N * sizeof(int), stream);
        k_fill<<<(E + 255) / 256, 256, 0, stream>>>(src, dst, row_ptr, cursor, dinv, col, wgt, E);

        // ---- stage 1 ----
        k_gather<<<gather_grid, 256, 0, stream>>>((const float4*)x_guide, dinv, row_ptr, cnt,
                                                  col, wgt, (float4*)agg, N);
        k_gemm_couple<<<gemm_grid, 256, 0, stream>>>(agg, Ws1, bs1, Wt1, bt1, x_main, out_main, N);

        // ---- stage 2 ----
        k_gather<<<gather_grid, 256, 0, stream>>>((const float4*)out_main, dinv, row_ptr, cnt,
                                                  col, wgt, (float4*)agg, N);
        k_gemm_couple<<<gemm_grid, 256, 0, stream>>>(agg, Ws2, bs2, Wt2, bt2, x_guide, out_guide, N);
    } else {
        // ---- fallback: round-1 atomic scatter path ----
        float* dinv_fb = (float*)d_ws;
        const int agg_init_grid = (N * 32 + 255) / 256;
        const int agg_edge_grid = (E * 32 + 255) / 256;

        hipMemsetAsync(d_ws, 0, (size_t)N * sizeof(int), stream);
        k_count<<<(E + 255) / 256, 256, 0, stream>>>(dst, (int*)d_ws, E);
        k_dinv_inplace<<<(N + 255) / 256, 256, 0, stream>>>(d_ws, N);

        k_agg_init<<<agg_init_grid, 256, 0, stream>>>((const float4*)x_guide, dinv_fb, (float4*)agg, N);
        k_agg_edges<<<agg_edge_grid, 256, 0, stream>>>(src, dst, dinv_fb, x_guide, agg, E);
        k_gemm_couple<<<gemm_grid, 256, 0, stream>>>(agg, Ws1, bs1, Wt1, bt1, x_main, out_main, N);

        k_agg_init<<<agg_init_grid, 256, 0, stream>>>((const float4*)out_main, dinv_fb, (float4*)agg, N);
        k_agg_edges<<<agg_edge_grid, 256, 0, stream>>>(src, dst, dinv_fb, out_main, agg, E);
        k_gemm_couple<<<gemm_grid, 256, 0, stream>>>(agg, Ws2, bs2, Wt2, bt2, x_guide, out_guide, N);
    }
}